// Round 3
// baseline (537.847 us; speedup 1.0000x reference)
//
#include <hip/hip_runtime.h>
#include <stdint.h>

typedef __attribute__((ext_vector_type(8))) short short8;
typedef __attribute__((ext_vector_type(4))) float floatx4;
typedef _Float16 half2v __attribute__((ext_vector_type(2)));

__device__ __forceinline__ float b2f(unsigned short u) {
  union { unsigned int i; float f; } v; v.i = ((unsigned int)u) << 16; return v.f;
}
__device__ __forceinline__ unsigned short f2b(float f) {
  union { float f; unsigned int i; } v; v.f = f;
  unsigned int i = v.i;
  return (unsigned short)((i + 0x7FFFu + ((i >> 16) & 1u)) >> 16);
}

// global -> LDS 16B per lane. lds_base must be wave-uniform; HW adds lane*16B.
__device__ __forceinline__ void stage16(const unsigned short* g, unsigned short* lds_base) {
  __builtin_amdgcn_global_load_lds((__attribute__((address_space(1))) const unsigned int*)g,
                                   (__attribute__((address_space(3))) unsigned int*)lds_base,
                                   16, 0, 0);
}

// ---------------------------------------------------------------------------
// BK=64 gemm core: C = A[M][K] @ Bt[N][K]^T, bf16 in, fp32 accum.
// LDS rows are 64 elem (128 B); chunk c (16 B) of row r stores global chunk
// c ^ (r & 7)  -> conflict-free ds_read_b128 (8 lanes per 4-bank group = floor)
// while keeping global_load_lds sources within aligned 128-B segments.
// 128x128 tile, 4 waves (2x2), 4x4 16x16x32 MFMA per wave, 2 k-steps/stage.
// ---------------------------------------------------------------------------
template<int ID>
__global__ __launch_bounds__(256) void gemm_bt(
    const unsigned short* __restrict__ A, const unsigned short* __restrict__ B,
    unsigned short* __restrict__ Cb, float* __restrict__ Cf,
    const float* __restrict__ rowdiv, const float* __restrict__ bias,
    int K, int lda, int ldb, int ldc,
    long long sA, long long sB, long long sC, long long sRD)
{
  const int tid  = threadIdx.x;
  const int lane = tid & 63;
  const int wave = tid >> 6;
  const int wr = wave >> 1, wc = wave & 1;
  const int m0 = blockIdx.y * 128;
  const int n0 = blockIdx.x * 128;
  const int bz = blockIdx.z;
  A += (long long)bz * sA;
  B += (long long)bz * sB;
  const float* rd = rowdiv ? rowdiv + (long long)bz * sRD : (const float*)0;

  __shared__ unsigned short As[128 * 64];
  __shared__ unsigned short Bs[128 * 64];

  floatx4 acc[4][4];
#pragma unroll
  for (int i = 0; i < 4; ++i)
#pragma unroll
    for (int j = 0; j < 4; ++j) acc[i][j] = floatx4{0.f, 0.f, 0.f, 0.f};

  const int r8 = lane >> 3;                  // row within an 8-row stage group
  const int sw = ((lane & 7) ^ r8) * 8;      // swizzled source chunk offset
  const unsigned short* gA = A + (long long)(m0 + wave * 32 + r8) * lda + sw;
  const unsigned short* gB = B + (long long)(n0 + wave * 32 + r8) * ldb + sw;
  unsigned short* lA = As + (wave * 32) * 64;
  unsigned short* lB = Bs + (wave * 32) * 64;

  const int l15 = lane & 15;
  const int q   = lane >> 4;       // 0..3 quad
  const int sx  = l15 & 7;         // xor key = row & 7

  for (int kt = 0; kt < K; kt += 64) {
    __syncthreads();
#pragma unroll
    for (int c = 0; c < 4; ++c) {
      stage16(gA + kt + (long long)c * 8 * lda, lA + c * 8 * 64);
      stage16(gB + kt + (long long)c * 8 * ldb, lB + c * 8 * 64);
    }
    __syncthreads();
#pragma unroll
    for (int s = 0; s < 2; ++s) {
      const int ch = ((s * 4 + q) ^ sx) * 8;
      short8 af[4], bfv[4];
#pragma unroll
      for (int i = 0; i < 4; ++i) af[i]  = *(const short8*)&As[(wr * 64 + i * 16 + l15) * 64 + ch];
#pragma unroll
      for (int j = 0; j < 4; ++j) bfv[j] = *(const short8*)&Bs[(wc * 64 + j * 16 + l15) * 64 + ch];
#pragma unroll
      for (int i = 0; i < 4; ++i)
#pragma unroll
        for (int j = 0; j < 4; ++j)
          acc[i][j] = __builtin_amdgcn_mfma_f32_16x16x32_bf16(af[i], bfv[j], acc[i][j], 0, 0, 0);
    }
  }

  const int q4 = (lane >> 4) * 4;
#pragma unroll
  for (int i = 0; i < 4; ++i) {
#pragma unroll
    for (int j = 0; j < 4; ++j) {
      const int col = n0 + wc * 64 + j * 16 + l15;
      const float bi = bias ? bias[col] : 0.0f;
#pragma unroll
      for (int r = 0; r < 4; ++r) {
        const int row = m0 + wr * 64 + i * 16 + q4 + r;
        float v = acc[i][j][r];
        if (rd) v = v * __builtin_amdgcn_rcpf(rd[row]);
        v += bi;
        if (Cb) Cb[(long long)bz * sC + (long long)row * ldc + col] = f2b(v);
        else    Cf[(long long)bz * sC + (long long)row * ldc + col] = v;
      }
    }
  }
}

// ---------------------------------------------------------------------------
// Fused scores + group + exp: W[b][m][n] = exp(q.k*scale) * (a + (1-a)*gw_m.gw_n)
// L[b*1024+m] += sum_n exp(q.k*scale).  Group factor computed FIRST and packed
// to fp16x2 (32 VGPRs) so only one 64-reg accumulator is live in the K-loop.
// ---------------------------------------------------------------------------
__global__ __launch_bounds__(256, 4) void score_weights(
    const unsigned short* __restrict__ qkv, const unsigned short* __restrict__ gw,
    unsigned short* __restrict__ Wout, float* __restrict__ L,
    const float* __restrict__ alpha)
{
  const int tid  = threadIdx.x;
  const int lane = tid & 63;
  const int wave = tid >> 6;
  const int wr = wave >> 1, wc = wave & 1;
  const int n0 = blockIdx.x * 128;
  const int m0 = blockIdx.y * 128;
  const int b  = blockIdx.z;

  const int l15 = lane & 15;
  const int q   = lane >> 4;
  const int sx  = l15 & 7;
  const int q8  = q * 8;

  // ---- group phase: gacc = gw_m . gw_n over K=64 (cols 49..63 zero) ----
  const unsigned short* gq = gw + ((long long)(b * 1024 + m0 + wr * 64)) * 64;
  const unsigned short* gk = gw + ((long long)(b * 1024 + n0 + wc * 64)) * 64;
  floatx4 gacc[4][4];
#pragma unroll
  for (int i = 0; i < 4; ++i)
#pragma unroll
    for (int j = 0; j < 4; ++j) gacc[i][j] = floatx4{0.f, 0.f, 0.f, 0.f};
#pragma unroll
  for (int ks = 0; ks < 2; ++ks) {
    short8 af[4], bfv[4];
#pragma unroll
    for (int i = 0; i < 4; ++i) af[i]  = *(const short8*)&gq[(long long)(i * 16 + l15) * 64 + ks * 32 + q8];
#pragma unroll
    for (int j = 0; j < 4; ++j) bfv[j] = *(const short8*)&gk[(long long)(j * 16 + l15) * 64 + ks * 32 + q8];
#pragma unroll
    for (int i = 0; i < 4; ++i)
#pragma unroll
      for (int j = 0; j < 4; ++j)
        gacc[i][j] = __builtin_amdgcn_mfma_f32_16x16x32_bf16(af[i], bfv[j], gacc[i][j], 0, 0, 0);
  }
  const float aa    = 1.0f / (1.0f + __expf(-alpha[0]));
  const float onema = 1.0f - aa;
  half2v gfp[4][4][2];
#pragma unroll
  for (int i = 0; i < 4; ++i)
#pragma unroll
    for (int j = 0; j < 4; ++j) {
      gfp[i][j][0] = half2v{(_Float16)(aa + onema * gacc[i][j][0]),
                            (_Float16)(aa + onema * gacc[i][j][1])};
      gfp[i][j][1] = half2v{(_Float16)(aa + onema * gacc[i][j][2]),
                            (_Float16)(aa + onema * gacc[i][j][3])};
    }

  // ---- main QK^T loop, BK=64 swizzled ----
  const unsigned short* Aq = qkv + ((long long)(b * 1024 + m0)) * 2304;        // q cols 0..767
  const unsigned short* Bk = qkv + ((long long)(b * 1024 + n0)) * 2304 + 768;  // k cols 768..1535

  __shared__ unsigned short As[128 * 64];
  __shared__ unsigned short Bs[128 * 64];

  floatx4 sacc[4][4];
#pragma unroll
  for (int i = 0; i < 4; ++i)
#pragma unroll
    for (int j = 0; j < 4; ++j) sacc[i][j] = floatx4{0.f, 0.f, 0.f, 0.f};

  const int r8 = lane >> 3;
  const int sw = ((lane & 7) ^ r8) * 8;
  const unsigned short* gA = Aq + (long long)(wave * 32 + r8) * 2304 + sw;
  const unsigned short* gB = Bk + (long long)(wave * 32 + r8) * 2304 + sw;
  unsigned short* lA = As + (wave * 32) * 64;
  unsigned short* lB = Bs + (wave * 32) * 64;

  for (int kt = 0; kt < 768; kt += 64) {
    __syncthreads();
#pragma unroll
    for (int c = 0; c < 4; ++c) {
      stage16(gA + kt + (long long)c * 8 * 2304, lA + c * 8 * 64);
      stage16(gB + kt + (long long)c * 8 * 2304, lB + c * 8 * 64);
    }
    __syncthreads();
#pragma unroll
    for (int s = 0; s < 2; ++s) {
      const int ch = ((s * 4 + q) ^ sx) * 8;
      short8 af[4], bfv[4];
#pragma unroll
      for (int i = 0; i < 4; ++i) af[i]  = *(const short8*)&As[(wr * 64 + i * 16 + l15) * 64 + ch];
#pragma unroll
      for (int j = 0; j < 4; ++j) bfv[j] = *(const short8*)&Bs[(wc * 64 + j * 16 + l15) * 64 + ch];
#pragma unroll
      for (int i = 0; i < 4; ++i)
#pragma unroll
        for (int j = 0; j < 4; ++j)
          sacc[i][j] = __builtin_amdgcn_mfma_f32_16x16x32_bf16(af[i], bfv[j], sacc[i][j], 0, 0, 0);
    }
  }

  const float scale = 0.03608439182435161f;  // 768^-0.5
  unsigned short* Wb = Wout + ((long long)b << 20);
  const int q4 = (lane >> 4) * 4;

  float ls[4][4];
#pragma unroll
  for (int i = 0; i < 4; ++i)
#pragma unroll
    for (int r = 0; r < 4; ++r) ls[i][r] = 0.0f;

#pragma unroll
  for (int i = 0; i < 4; ++i) {
#pragma unroll
    for (int j = 0; j < 4; ++j) {
      const int col = n0 + wc * 64 + j * 16 + l15;
#pragma unroll
      for (int r = 0; r < 4; ++r) {
        const int row = m0 + wr * 64 + i * 16 + q4 + r;
        const float e = __expf(sacc[i][j][r] * scale);
        const float g = (float)gfp[i][j][r >> 1][r & 1];
        Wb[(long long)row * 1024 + col] = f2b(e * g);
        ls[i][r] += e;
      }
    }
  }
#pragma unroll
  for (int i = 0; i < 4; ++i) {
#pragma unroll
    for (int r = 0; r < 4; ++r) {
      float v = ls[i][r];
      v += __shfl_xor(v, 1, 64);
      v += __shfl_xor(v, 2, 64);
      v += __shfl_xor(v, 4, 64);
      v += __shfl_xor(v, 8, 64);
      if (l15 == 0) {
        const int row = m0 + wr * 64 + i * 16 + q4 + r;
        atomicAdd(&L[b * 1024 + row], v);
      }
    }
  }
}

// gw[row][0..63] = softmax(q_row @ W_gp) padded with zeros (cols 49..63).
__global__ __launch_bounds__(256) void gw_kernel(
    const unsigned short* __restrict__ qkv, const unsigned short* __restrict__ WgpT,
    unsigned short* __restrict__ gw)
{
  const int wave = threadIdx.x >> 6;
  const int lane = threadIdx.x & 63;
  const long long row = (long long)blockIdx.x * 4 + wave;
  const unsigned short* q = qkv + row * 2304;
  float qv[12];
#pragma unroll
  for (int j = 0; j < 12; ++j) qv[j] = b2f(q[lane + 64 * j]);

  float logit = -1e30f;
  for (int g = 0; g < 49; ++g) {
    const unsigned short* wg = WgpT + g * 768;
    float acc = 0.0f;
#pragma unroll
    for (int j = 0; j < 12; ++j) acc += qv[j] * b2f(wg[lane + 64 * j]);
#pragma unroll
    for (int m = 1; m < 64; m <<= 1) acc += __shfl_xor(acc, m, 64);
    if (lane == g) logit = acc;
  }
  float mx = logit;
#pragma unroll
  for (int m = 1; m < 64; m <<= 1) mx = fmaxf(mx, __shfl_xor(mx, m, 64));
  const float e = (lane < 49) ? __expf(logit - mx) : 0.0f;
  float s = e;
#pragma unroll
  for (int m = 1; m < 64; m <<= 1) s += __shfl_xor(s, m, 64);
  gw[row * 64 + lane] = f2b(e / s);
}

__global__ void convert_f2b(const float* __restrict__ in, unsigned short* __restrict__ out, long long n)
{
  long long i = ((long long)blockIdx.x * 256 + threadIdx.x) * 4;
  if (i + 3 >= n) {
    for (long long k = i; k < n; ++k) out[k] = f2b(in[k]);
    return;
  }
  float4 v = *(const float4*)(in + i);
  out[i + 0] = f2b(v.x);
  out[i + 1] = f2b(v.y);
  out[i + 2] = f2b(v.z);
  out[i + 3] = f2b(v.w);
}

__global__ void transpose_f2b(const float* __restrict__ in, unsigned short* __restrict__ out,
                              int R, int C, int ldin, int ldout)
{
  __shared__ unsigned short t[32][33];
  const int c0 = blockIdx.x * 32, r0 = blockIdx.y * 32;
  for (int i = threadIdx.y; i < 32; i += 8) {
    const int r = r0 + i, c = c0 + threadIdx.x;
    if (r < R && c < C) t[i][threadIdx.x] = f2b(in[(long long)r * ldin + c]);
  }
  __syncthreads();
  for (int i = threadIdx.y; i < 32; i += 8) {
    const int r = c0 + i, c = r0 + threadIdx.x;
    if (r < C && c < R) out[(long long)r * ldout + c] = t[threadIdx.x][i];
  }
}

__global__ void transpose_bf16(const unsigned short* __restrict__ in, unsigned short* __restrict__ out,
                               int R, int C, int ldin, int ldout, long long sIn, long long sOut)
{
  __shared__ unsigned short t[32][33];
  in  += (long long)blockIdx.z * sIn;
  out += (long long)blockIdx.z * sOut;
  const int c0 = blockIdx.x * 32, r0 = blockIdx.y * 32;
  for (int i = threadIdx.y; i < 32; i += 8) {
    const int r = r0 + i, c = c0 + threadIdx.x;
    if (r < R && c < C) t[i][threadIdx.x] = in[(long long)r * ldin + c];
  }
  __syncthreads();
  for (int i = threadIdx.y; i < 32; i += 8) {
    const int r = c0 + i, c = r0 + threadIdx.x;
    if (r < C && c < R) out[(long long)r * ldout + c] = t[threadIdx.x][i];
  }
}

extern "C" void kernel_launch(void* const* d_in, const int* in_sizes, int n_in,
                              void* d_out, int out_size, void* d_ws, size_t ws_size,
                              hipStream_t stream)
{
  const float* x      = (const float*)d_in[0];
  const float* W_qkv  = (const float*)d_in[1];
  const float* b_qkv  = (const float*)d_in[2];
  const float* W_proj = (const float*)d_in[3];
  const float* b_proj = (const float*)d_in[4];
  const float* W_gp   = (const float*)d_in[5];
  const float* alpha  = (const float*)d_in[6];

  char* p = (char*)d_ws;
  auto alloc = [&](size_t bytes) { char* r = p; p += (bytes + 255) & ~255ULL; return r; };
  unsigned short* qkv    = (unsigned short*)alloc(16384ULL * 2304 * 2);   // q|k|v interleaved rows
  unsigned short* xb     = (unsigned short*)alloc(16384ULL * 768 * 2);
  unsigned short* WqkvT  = (unsigned short*)alloc(2304ULL * 768 * 2);
  unsigned short* WprojT = (unsigned short*)alloc(768ULL * 768 * 2);
  unsigned short* WgpT   = (unsigned short*)alloc(49ULL * 768 * 2);
  unsigned short* gwbuf  = (unsigned short*)alloc(16384ULL * 64 * 2);
  float*          Lbuf   = (float*)alloc(16384ULL * 4);
  unsigned short* wmat   = (unsigned short*)alloc(16ULL * 1024 * 1024 * 2);
  unsigned short* vT     = (unsigned short*)alloc(16ULL * 768 * 1024 * 2);

  const dim3 blk256(256);
  const dim3 tb(32, 8);

  // input conversions / transposes (fp32 -> bf16)
  convert_f2b<<<dim3(12288), blk256, 0, stream>>>(x, xb, 16384LL * 768);
  transpose_f2b<<<dim3(72, 24), tb, 0, stream>>>(W_qkv, WqkvT, 768, 2304, 2304, 768);
  transpose_f2b<<<dim3(24, 24), tb, 0, stream>>>(W_proj, WprojT, 768, 768, 768, 768);
  transpose_f2b<<<dim3(2, 24), tb, 0, stream>>>(W_gp, WgpT, 768, 49, 49, 768);

  // qkv = x @ W_qkv + b_qkv   (M=16384, N=2304, K=768), bf16 out
  gemm_bt<0><<<dim3(18, 128, 1), blk256, 0, stream>>>(xb, WqkvT, qkv, (float*)0, (const float*)0, b_qkv,
                                                      768, 768, 768, 2304, 0, 0, 0, 0);

  // vT[b][768][1024] = v^T (v = qkv cols 1536..2303)
  transpose_bf16<<<dim3(24, 32, 16), tb, 0, stream>>>(qkv + 1536, vT, 1024, 768, 2304, 1024,
                                                      1024LL * 2304, 768LL * 1024);

  // gw = softmax(q @ W_gp), padded to 64
  gw_kernel<<<dim3(4096), blk256, 0, stream>>>(qkv, WgpT, gwbuf);

  hipMemsetAsync(Lbuf, 0, 16384 * 4, stream);

  // weights (unnormalized) + L
  score_weights<<<dim3(8, 8, 16), blk256, 0, stream>>>(qkv, gwbuf, wmat, Lbuf, alpha);

  // attn_out = (weights @ v) / L  -> written into qkv's dead k-columns (bf16)
  gemm_bt<1><<<dim3(6, 8, 16), blk256, 0, stream>>>(wmat, vT, qkv + 768, (float*)0, Lbuf, (const float*)0,
                                                    1024, 1024, 1024, 2304,
                                                    1024LL * 1024, 768LL * 1024, 1024LL * 2304, 1024);

  // out = attn_out @ W_proj + b_proj  (fp32 out)
  gemm_bt<2><<<dim3(6, 128, 1), blk256, 0, stream>>>(qkv + 768, WprojT, (unsigned short*)0, (float*)d_out,
                                                     (const float*)0, b_proj,
                                                     768, 2304, 768, 768, 0, 0, 0, 0);
}

// Round 4
// 467.135 us; speedup vs baseline: 1.1514x; 1.1514x over previous
//
#include <hip/hip_runtime.h>
#include <stdint.h>

typedef __attribute__((ext_vector_type(8))) short short8;
typedef __attribute__((ext_vector_type(4))) short short4v;
typedef __attribute__((ext_vector_type(4))) float floatx4;
typedef _Float16 half2v __attribute__((ext_vector_type(2)));

__device__ __forceinline__ float b2f(unsigned short u) {
  union { unsigned int i; float f; } v; v.i = ((unsigned int)u) << 16; return v.f;
}
__device__ __forceinline__ unsigned short f2b(float f) {
  union { float f; unsigned int i; } v; v.f = f;
  unsigned int i = v.i;
  return (unsigned short)((i + 0x7FFFu + ((i >> 16) & 1u)) >> 16);
}
__device__ __forceinline__ short4v pack4(float a, float b, float c, float d) {
  short4v r;
  r[0] = (short)f2b(a); r[1] = (short)f2b(b); r[2] = (short)f2b(c); r[3] = (short)f2b(d);
  return r;
}

// global -> LDS 16B per lane. lds_base must be wave-uniform; HW adds lane*16B.
__device__ __forceinline__ void stage16(const unsigned short* g, unsigned short* lds_base) {
  __builtin_amdgcn_global_load_lds((__attribute__((address_space(1))) const unsigned int*)g,
                                   (__attribute__((address_space(3))) unsigned int*)lds_base,
                                   16, 0, 0);
}

// ---------------------------------------------------------------------------
// BK=32 gemm core: C = A[M][K] @ Bt[N][K]^T, bf16 in, fp32 accum.
// LDS rows 32 elem (64 B) in 4 chunks of 16 B; chunk c of row r stores global
// chunk c ^ (r&3) -> conflict-free ds_read_b128 (verified 0 conflicts w/ the
// same pattern in r3). MFMA operands SWAPPED (B-frag first) so C rows sit on
// lanes and 4 consecutive cols per lane -> 8-B packed stores.
// 128x128 tile, 4 waves (2x2), 4x4 16x16x32 MFMA per wave.
// ---------------------------------------------------------------------------
template<int ID>
__global__ __launch_bounds__(256) void gemm_bt(
    const unsigned short* __restrict__ A, const unsigned short* __restrict__ B,
    unsigned short* __restrict__ Cb, float* __restrict__ Cf,
    const float* __restrict__ rowdiv, const float* __restrict__ bias,
    int K, int lda, int ldb, int ldc,
    long long sA, long long sB, long long sC, long long sRD)
{
  const int tid  = threadIdx.x;
  const int lane = tid & 63;
  const int wave = tid >> 6;
  const int wr = wave >> 1, wc = wave & 1;
  const int m0 = blockIdx.y * 128;
  const int n0 = blockIdx.x * 128;
  const int bz = blockIdx.z;
  A += (long long)bz * sA;
  B += (long long)bz * sB;
  const float* rd = rowdiv ? rowdiv + (long long)bz * sRD : (const float*)0;

  __shared__ unsigned short As[128 * 32];
  __shared__ unsigned short Bs[128 * 32];

  floatx4 acc[4][4];
#pragma unroll
  for (int i = 0; i < 4; ++i)
#pragma unroll
    for (int j = 0; j < 4; ++j) acc[i][j] = floatx4{0.f, 0.f, 0.f, 0.f};

  const int r4 = lane >> 2;                       // staging row within 16-row group
  const int sw = ((lane & 3) ^ (r4 & 3)) * 8;     // swizzled source chunk
  const unsigned short* ga0 = A + (long long)(m0 + wave * 32 + r4) * lda + sw;
  const unsigned short* ga1 = ga0 + 16LL * lda;
  const unsigned short* gb0 = B + (long long)(n0 + wave * 32 + r4) * ldb + sw;
  const unsigned short* gb1 = gb0 + 16LL * ldb;
  unsigned short* lA0 = As + (wave * 32) * 32;
  unsigned short* lA1 = As + (wave * 32 + 16) * 32;
  unsigned short* lB0 = Bs + (wave * 32) * 32;
  unsigned short* lB1 = Bs + (wave * 32 + 16) * 32;

  const int l15 = lane & 15;
  const int q   = lane >> 4;
  const int ch  = (q ^ (l15 & 3)) * 8;            // swizzled read chunk

  for (int kt = 0; kt < K; kt += 32) {
    __syncthreads();
    stage16(ga0 + kt, lA0);
    stage16(ga1 + kt, lA1);
    stage16(gb0 + kt, lB0);
    stage16(gb1 + kt, lB1);
    __syncthreads();
    short8 af[4], bfv[4];
#pragma unroll
    for (int i = 0; i < 4; ++i) af[i]  = *(const short8*)&As[(wr * 64 + i * 16 + l15) * 32 + ch];
#pragma unroll
    for (int j = 0; j < 4; ++j) bfv[j] = *(const short8*)&Bs[(wc * 64 + j * 16 + l15) * 32 + ch];
#pragma unroll
    for (int i = 0; i < 4; ++i)
#pragma unroll
      for (int j = 0; j < 4; ++j)
        acc[i][j] = __builtin_amdgcn_mfma_f32_16x16x32_bf16(bfv[j], af[i], acc[i][j], 0, 0, 0);
  }

  // Epilogue: lane holds C[row = m0+wr*64+i*16+l15][col = n0+wc*64+j*16+q*4 + r], r=0..3
#pragma unroll
  for (int i = 0; i < 4; ++i) {
    const int row = m0 + wr * 64 + i * 16 + l15;
    const float rcp = rd ? __builtin_amdgcn_rcpf(rd[row]) : 1.0f;
#pragma unroll
    for (int j = 0; j < 4; ++j) {
      const int colb = n0 + wc * 64 + j * 16 + q * 4;
      floatx4 v = acc[i][j];
      if (rd) { v[0] *= rcp; v[1] *= rcp; v[2] *= rcp; v[3] *= rcp; }
      if (bias) {
        const float4 bi = *(const float4*)&bias[colb];
        v[0] += bi.x; v[1] += bi.y; v[2] += bi.z; v[3] += bi.w;
      }
      if (Cb) *(short4v*)&Cb[(long long)bz * sC + (long long)row * ldc + colb] = pack4(v[0], v[1], v[2], v[3]);
      else    *(floatx4*)&Cf[(long long)bz * sC + (long long)row * ldc + colb] = v;
    }
  }
}

// ---------------------------------------------------------------------------
// Fused scores + group + exp: W[b][m][n] = exp(q.k*scale) * (a + (1-a)*gw_m.gw_n)
// L[b*1024+m] += sum_n exp(q.k*scale).  Group factor computed first, packed
// fp16x2. Swapped-operand MFMA throughout (rows on lanes).
// ---------------------------------------------------------------------------
__global__ __launch_bounds__(256) void score_weights(
    const unsigned short* __restrict__ qkv, const unsigned short* __restrict__ gw,
    unsigned short* __restrict__ Wout, float* __restrict__ L,
    const float* __restrict__ alpha)
{
  const int tid  = threadIdx.x;
  const int lane = tid & 63;
  const int wave = tid >> 6;
  const int wr = wave >> 1, wc = wave & 1;
  const int n0 = blockIdx.x * 128;
  const int m0 = blockIdx.y * 128;
  const int b  = blockIdx.z;

  const int l15 = lane & 15;
  const int q   = lane >> 4;
  const int q8  = q * 8;
  const int ch  = (q ^ (l15 & 3)) * 8;

  // ---- group phase: direct-from-global frags, K=64 (cols 49..63 zero) ----
  const unsigned short* gq = gw + ((long long)(b * 1024 + m0 + wr * 64)) * 64;
  const unsigned short* gk = gw + ((long long)(b * 1024 + n0 + wc * 64)) * 64;
  floatx4 gacc[4][4];
#pragma unroll
  for (int i = 0; i < 4; ++i)
#pragma unroll
    for (int j = 0; j < 4; ++j) gacc[i][j] = floatx4{0.f, 0.f, 0.f, 0.f};
#pragma unroll
  for (int ks = 0; ks < 2; ++ks) {
    short8 af[4], bfv[4];
#pragma unroll
    for (int i = 0; i < 4; ++i) af[i]  = *(const short8*)&gq[(long long)(i * 16 + l15) * 64 + ks * 32 + q8];
#pragma unroll
    for (int j = 0; j < 4; ++j) bfv[j] = *(const short8*)&gk[(long long)(j * 16 + l15) * 64 + ks * 32 + q8];
#pragma unroll
    for (int i = 0; i < 4; ++i)
#pragma unroll
      for (int j = 0; j < 4; ++j)
        gacc[i][j] = __builtin_amdgcn_mfma_f32_16x16x32_bf16(bfv[j], af[i], gacc[i][j], 0, 0, 0);
  }
  const float aa    = 1.0f / (1.0f + __expf(-alpha[0]));
  const float onema = 1.0f - aa;
  half2v gfp[4][4][2];
#pragma unroll
  for (int i = 0; i < 4; ++i)
#pragma unroll
    for (int j = 0; j < 4; ++j) {
      gfp[i][j][0] = half2v{(_Float16)(aa + onema * gacc[i][j][0]),
                            (_Float16)(aa + onema * gacc[i][j][1])};
      gfp[i][j][1] = half2v{(_Float16)(aa + onema * gacc[i][j][2]),
                            (_Float16)(aa + onema * gacc[i][j][3])};
    }

  // ---- QK^T loop, BK=32 swizzled ----
  const unsigned short* Aq = qkv + ((long long)(b * 1024 + m0)) * 2304;        // q cols 0..767
  const unsigned short* Bk = qkv + ((long long)(b * 1024 + n0)) * 2304 + 768;  // k cols 768..1535

  __shared__ unsigned short As[128 * 32];
  __shared__ unsigned short Bs[128 * 32];

  floatx4 sacc[4][4];
#pragma unroll
  for (int i = 0; i < 4; ++i)
#pragma unroll
    for (int j = 0; j < 4; ++j) sacc[i][j] = floatx4{0.f, 0.f, 0.f, 0.f};

  const int r4 = lane >> 2;
  const int sw = ((lane & 3) ^ (r4 & 3)) * 8;
  const unsigned short* ga0 = Aq + (long long)(wave * 32 + r4) * 2304 + sw;
  const unsigned short* ga1 = ga0 + 16LL * 2304;
  const unsigned short* gb0 = Bk + (long long)(wave * 32 + r4) * 2304 + sw;
  const unsigned short* gb1 = gb0 + 16LL * 2304;
  unsigned short* lA0 = As + (wave * 32) * 32;
  unsigned short* lA1 = As + (wave * 32 + 16) * 32;
  unsigned short* lB0 = Bs + (wave * 32) * 32;
  unsigned short* lB1 = Bs + (wave * 32 + 16) * 32;

  for (int kt = 0; kt < 768; kt += 32) {
    __syncthreads();
    stage16(ga0 + kt, lA0);
    stage16(ga1 + kt, lA1);
    stage16(gb0 + kt, lB0);
    stage16(gb1 + kt, lB1);
    __syncthreads();
    short8 af[4], bfv[4];
#pragma unroll
    for (int i = 0; i < 4; ++i) af[i]  = *(const short8*)&As[(wr * 64 + i * 16 + l15) * 32 + ch];
#pragma unroll
    for (int j = 0; j < 4; ++j) bfv[j] = *(const short8*)&Bs[(wc * 64 + j * 16 + l15) * 32 + ch];
#pragma unroll
    for (int i = 0; i < 4; ++i)
#pragma unroll
      for (int j = 0; j < 4; ++j)
        sacc[i][j] = __builtin_amdgcn_mfma_f32_16x16x32_bf16(bfv[j], af[i], sacc[i][j], 0, 0, 0);
  }

  const float scale = 0.03608439182435161f;  // 768^-0.5
  unsigned short* Wb = Wout + ((long long)b << 20);

#pragma unroll
  for (int i = 0; i < 4; ++i) {
    const int row = m0 + wr * 64 + i * 16 + l15;
    float ls = 0.0f;
#pragma unroll
    for (int j = 0; j < 4; ++j) {
      const int colb = n0 + wc * 64 + j * 16 + q * 4;
      float e0 = __expf(sacc[i][j][0] * scale);
      float e1 = __expf(sacc[i][j][1] * scale);
      float e2 = __expf(sacc[i][j][2] * scale);
      float e3 = __expf(sacc[i][j][3] * scale);
      ls += (e0 + e1) + (e2 + e3);
      *(short4v*)&Wb[(long long)row * 1024 + colb] =
        pack4(e0 * (float)gfp[i][j][0][0], e1 * (float)gfp[i][j][0][1],
              e2 * (float)gfp[i][j][1][0], e3 * (float)gfp[i][j][1][1]);
    }
    // sum over the 4 quads sharing this row (lanes l15, l15+16, +32, +48)
    ls += __shfl_xor(ls, 16, 64);
    ls += __shfl_xor(ls, 32, 64);
    if (lane < 16) atomicAdd(&L[b * 1024 + row], ls);
  }
}

// gw[row][0..63] = softmax(q_row @ W_gp) padded with zeros (cols 49..63).
__global__ __launch_bounds__(256) void gw_kernel(
    const unsigned short* __restrict__ qkv, const unsigned short* __restrict__ WgpT,
    unsigned short* __restrict__ gw)
{
  const int wave = threadIdx.x >> 6;
  const int lane = threadIdx.x & 63;
  const long long row = (long long)blockIdx.x * 4 + wave;
  const unsigned short* q = qkv + row * 2304;
  float qv[12];
#pragma unroll
  for (int j = 0; j < 12; ++j) qv[j] = b2f(q[lane + 64 * j]);

  float logit = -1e30f;
  for (int g = 0; g < 49; ++g) {
    const unsigned short* wg = WgpT + g * 768;
    float acc = 0.0f;
#pragma unroll
    for (int j = 0; j < 12; ++j) acc += qv[j] * b2f(wg[lane + 64 * j]);
#pragma unroll
    for (int m = 1; m < 64; m <<= 1) acc += __shfl_xor(acc, m, 64);
    if (lane == g) logit = acc;
  }
  float mx = logit;
#pragma unroll
  for (int m = 1; m < 64; m <<= 1) mx = fmaxf(mx, __shfl_xor(mx, m, 64));
  const float e = (lane < 49) ? __expf(logit - mx) : 0.0f;
  float s = e;
#pragma unroll
  for (int m = 1; m < 64; m <<= 1) s += __shfl_xor(s, m, 64);
  gw[row * 64 + lane] = f2b(e / s);
}

__global__ void convert_f2b(const float* __restrict__ in, unsigned short* __restrict__ out, long long n)
{
  long long i = ((long long)blockIdx.x * 256 + threadIdx.x) * 4;
  if (i + 3 >= n) {
    for (long long k = i; k < n; ++k) out[k] = f2b(in[k]);
    return;
  }
  float4 v = *(const float4*)(in + i);
  out[i + 0] = f2b(v.x);
  out[i + 1] = f2b(v.y);
  out[i + 2] = f2b(v.z);
  out[i + 3] = f2b(v.w);
}

__global__ void transpose_f2b(const float* __restrict__ in, unsigned short* __restrict__ out,
                              int R, int C, int ldin, int ldout)
{
  __shared__ unsigned short t[32][33];
  const int c0 = blockIdx.x * 32, r0 = blockIdx.y * 32;
  for (int i = threadIdx.y; i < 32; i += 8) {
    const int r = r0 + i, c = c0 + threadIdx.x;
    if (r < R && c < C) t[i][threadIdx.x] = f2b(in[(long long)r * ldin + c]);
  }
  __syncthreads();
  for (int i = threadIdx.y; i < 32; i += 8) {
    const int r = c0 + i, c = r0 + threadIdx.x;
    if (r < C && c < R) out[(long long)r * ldout + c] = t[threadIdx.x][i];
  }
}

__global__ void transpose_bf16(const unsigned short* __restrict__ in, unsigned short* __restrict__ out,
                               int R, int C, int ldin, int ldout, long long sIn, long long sOut)
{
  __shared__ unsigned short t[32][33];
  in  += (long long)blockIdx.z * sIn;
  out += (long long)blockIdx.z * sOut;
  const int c0 = blockIdx.x * 32, r0 = blockIdx.y * 32;
  for (int i = threadIdx.y; i < 32; i += 8) {
    const int r = r0 + i, c = c0 + threadIdx.x;
    if (r < R && c < C) t[i][threadIdx.x] = in[(long long)r * ldin + c];
  }
  __syncthreads();
  for (int i = threadIdx.y; i < 32; i += 8) {
    const int r = c0 + i, c = r0 + threadIdx.x;
    if (r < C && c < R) out[(long long)r * ldout + c] = t[threadIdx.x][i];
  }
}

extern "C" void kernel_launch(void* const* d_in, const int* in_sizes, int n_in,
                              void* d_out, int out_size, void* d_ws, size_t ws_size,
                              hipStream_t stream)
{
  const float* x      = (const float*)d_in[0];
  const float* W_qkv  = (const float*)d_in[1];
  const float* b_qkv  = (const float*)d_in[2];
  const float* W_proj = (const float*)d_in[3];
  const float* b_proj = (const float*)d_in[4];
  const float* W_gp   = (const float*)d_in[5];
  const float* alpha  = (const float*)d_in[6];

  char* p = (char*)d_ws;
  auto alloc = [&](size_t bytes) { char* r = p; p += (bytes + 255) & ~255ULL; return r; };
  unsigned short* qkv    = (unsigned short*)alloc(16384ULL * 2304 * 2);   // q|k|v interleaved rows
  unsigned short* xb     = (unsigned short*)alloc(16384ULL * 768 * 2);
  unsigned short* WqkvT  = (unsigned short*)alloc(2304ULL * 768 * 2);
  unsigned short* WprojT = (unsigned short*)alloc(768ULL * 768 * 2);
  unsigned short* WgpT   = (unsigned short*)alloc(49ULL * 768 * 2);
  unsigned short* gwbuf  = (unsigned short*)alloc(16384ULL * 64 * 2);
  float*          Lbuf   = (float*)alloc(16384ULL * 4);
  unsigned short* wmat   = (unsigned short*)alloc(16ULL * 1024 * 1024 * 2);
  unsigned short* vT     = (unsigned short*)alloc(16ULL * 768 * 1024 * 2);

  const dim3 blk256(256);
  const dim3 tb(32, 8);

  // input conversions / transposes (fp32 -> bf16)
  convert_f2b<<<dim3(12288), blk256, 0, stream>>>(x, xb, 16384LL * 768);
  transpose_f2b<<<dim3(72, 24), tb, 0, stream>>>(W_qkv, WqkvT, 768, 2304, 2304, 768);
  transpose_f2b<<<dim3(24, 24), tb, 0, stream>>>(W_proj, WprojT, 768, 768, 768, 768);
  transpose_f2b<<<dim3(2, 24), tb, 0, stream>>>(W_gp, WgpT, 768, 49, 49, 768);

  // qkv = x @ W_qkv + b_qkv   (M=16384, N=2304, K=768), bf16 out
  gemm_bt<0><<<dim3(18, 128, 1), blk256, 0, stream>>>(xb, WqkvT, qkv, (float*)0, (const float*)0, b_qkv,
                                                      768, 768, 768, 2304, 0, 0, 0, 0);

  // vT[b][768][1024] = v^T (v = qkv cols 1536..2303)
  transpose_bf16<<<dim3(24, 32, 16), tb, 0, stream>>>(qkv + 1536, vT, 1024, 768, 2304, 1024,
                                                      1024LL * 2304, 768LL * 1024);

  // gw = softmax(q @ W_gp), padded to 64
  gw_kernel<<<dim3(4096), blk256, 0, stream>>>(qkv, WgpT, gwbuf);

  hipMemsetAsync(Lbuf, 0, 16384 * 4, stream);

  // weights (unnormalized) + L
  score_weights<<<dim3(8, 8, 16), blk256, 0, stream>>>(qkv, gwbuf, wmat, Lbuf, alpha);

  // attn_out = (weights @ v) / L  -> written into qkv's dead k-columns (bf16)
  gemm_bt<1><<<dim3(6, 8, 16), blk256, 0, stream>>>(wmat, vT, qkv + 768, (float*)0, Lbuf, (const float*)0,
                                                    1024, 1024, 1024, 2304,
                                                    1024LL * 1024, 768LL * 1024, 1024LL * 2304, 1024);

  // out = attn_out @ W_proj + b_proj  (fp32 out)
  gemm_bt<2><<<dim3(6, 128, 1), blk256, 0, stream>>>(qkv + 768, WprojT, (unsigned short*)0, (float*)d_out,
                                                     (const float*)0, b_proj,
                                                     768, 2304, 768, 768, 0, 0, 0, 0);
}

// Round 5
// 463.352 us; speedup vs baseline: 1.1608x; 1.0082x over previous
//
#include <hip/hip_runtime.h>
#include <stdint.h>

typedef __attribute__((ext_vector_type(8))) short short8;
typedef __attribute__((ext_vector_type(4))) short short4v;
typedef __attribute__((ext_vector_type(4))) float floatx4;
typedef _Float16 half2v __attribute__((ext_vector_type(2)));

__device__ __forceinline__ float b2f(unsigned short u) {
  union { unsigned int i; float f; } v; v.i = ((unsigned int)u) << 16; return v.f;
}
__device__ __forceinline__ unsigned short f2b(float f) {
  union { float f; unsigned int i; } v; v.f = f;
  unsigned int i = v.i;
  return (unsigned short)((i + 0x7FFFu + ((i >> 16) & 1u)) >> 16);
}
__device__ __forceinline__ short4v pack4(float a, float b, float c, float d) {
  short4v r;
  r[0] = (short)f2b(a); r[1] = (short)f2b(b); r[2] = (short)f2b(c); r[3] = (short)f2b(d);
  return r;
}

// global -> LDS 16B per lane. lds_base wave-uniform; HW adds lane*16B.
__device__ __forceinline__ void stage16(const unsigned short* g, unsigned short* lds_base) {
  __builtin_amdgcn_global_load_lds((__attribute__((address_space(1))) const unsigned int*)g,
                                   (__attribute__((address_space(3))) unsigned int*)lds_base,
                                   16, 0, 0);
}

// ---------------------------------------------------------------------------
// BK=32 gemm core with PAIRED-ROW LDS swizzle.
// LDS: 64 physical rows x 64 elem (128 B). Physical row P holds global rows
// 2P,2P+1; chunk p of P = global(row 2P+e, chunk q) with p=(q+4e)^(P&7).
// Per 32-lane half each 4-bank group gets 2 lanes -> conflict-free (r3: 0).
// MFMA operands swapped (B-frag first): C rows on lanes, 4 consecutive cols
// per lane -> 8-B packed stores.
// ---------------------------------------------------------------------------
template<int ID>
__global__ __launch_bounds__(256) void gemm_bt(
    const unsigned short* __restrict__ A, const unsigned short* __restrict__ B,
    unsigned short* __restrict__ Cb, float* __restrict__ Cf,
    const float* __restrict__ rowdiv, const float* __restrict__ bias,
    int K, int lda, int ldb, int ldc,
    long long sA, long long sB, long long sC, long long sRD)
{
  const int tid  = threadIdx.x;
  const int lane = tid & 63;
  const int wave = tid >> 6;
  const int wr = wave >> 1, wc = wave & 1;
  const int m0 = blockIdx.y * 128;
  const int n0 = blockIdx.x * 128;
  const int bz = blockIdx.z;
  A += (long long)bz * sA;
  B += (long long)bz * sB;
  const float* rd = rowdiv ? rowdiv + (long long)bz * sRD : (const float*)0;

  __shared__ unsigned short As[128 * 32];
  __shared__ unsigned short Bs[128 * 32];

  floatx4 acc[4][4];
#pragma unroll
  for (int i = 0; i < 4; ++i)
#pragma unroll
    for (int j = 0; j < 4; ++j) acc[i][j] = floatx4{0.f, 0.f, 0.f, 0.f};

  // staging source map: lane l -> physical (P=l>>3, p=l&7); t=p^(l>>3);
  // source row_local = 2*(l>>3)+(t>>2), chunk = t&3.
  const int t    = (lane & 7) ^ (lane >> 3);
  const int srow = 2 * (lane >> 3) + (t >> 2);
  const int scol = (t & 3) * 8;
  const unsigned short* ga0 = A + (long long)(m0 + wave * 32 + srow) * lda + scol;
  const unsigned short* ga1 = ga0 + 16LL * lda;
  const unsigned short* gb0 = B + (long long)(n0 + wave * 32 + srow) * ldb + scol;
  const unsigned short* gb1 = gb0 + 16LL * ldb;
  unsigned short* lA0 = As + wave * 1024;          // physical rows wave*16..+7
  unsigned short* lA1 = lA0 + 512;                 // +8 physical rows
  unsigned short* lB0 = Bs + wave * 1024;
  unsigned short* lB1 = lB0 + 512;

  const int l15  = lane & 15;
  const int q    = lane >> 4;
  // read map: global row base+l15, chunk q -> physical P=base/2+(l15>>1),
  // p=(q+4*(l15&1))^(l15>>1)  (tile-invariant)
  const int rofs = (l15 >> 1) * 64 + (((q + 4 * (l15 & 1)) ^ (l15 >> 1)) * 8);

  for (int kt = 0; kt < K; kt += 32) {
    __syncthreads();
    stage16(ga0 + kt, lA0);
    stage16(ga1 + kt, lA1);
    stage16(gb0 + kt, lB0);
    stage16(gb1 + kt, lB1);
    __syncthreads();
    short8 af[4], bfv[4];
#pragma unroll
    for (int i = 0; i < 4; ++i) af[i]  = *(const short8*)&As[(wr * 32 + i * 8) * 64 + rofs];
#pragma unroll
    for (int j = 0; j < 4; ++j) bfv[j] = *(const short8*)&Bs[(wc * 32 + j * 8) * 64 + rofs];
#pragma unroll
    for (int i = 0; i < 4; ++i)
#pragma unroll
      for (int j = 0; j < 4; ++j)
        acc[i][j] = __builtin_amdgcn_mfma_f32_16x16x32_bf16(bfv[j], af[i], acc[i][j], 0, 0, 0);
  }

  // Epilogue: lane holds C[row=m0+wr*64+i*16+l15][cols n0+wc*64+j*16+q*4 .. +3]
#pragma unroll
  for (int i = 0; i < 4; ++i) {
    const int row = m0 + wr * 64 + i * 16 + l15;
    const float rcp = rd ? __builtin_amdgcn_rcpf(rd[row]) : 1.0f;
#pragma unroll
    for (int j = 0; j < 4; ++j) {
      const int colb = n0 + wc * 64 + j * 16 + q * 4;
      floatx4 v = acc[i][j];
      if (rd) { v[0] *= rcp; v[1] *= rcp; v[2] *= rcp; v[3] *= rcp; }
      if (bias) {
        const float4 bi = *(const float4*)&bias[colb];
        v[0] += bi.x; v[1] += bi.y; v[2] += bi.z; v[3] += bi.w;
      }
      if (Cb) *(short4v*)&Cb[(long long)bz * sC + (long long)row * ldc + colb] = pack4(v[0], v[1], v[2], v[3]);
      else    *(floatx4*)&Cf[(long long)bz * sC + (long long)row * ldc + colb] = v;
    }
  }
}

// ---------------------------------------------------------------------------
// Fused scores + group + exp, same paired-row swizzle in the QK^T loop.
// W[b][m][n] = exp(q.k*scale) * (a + (1-a)*gw_m.gw_n);  L[row] += sum exp.
// ---------------------------------------------------------------------------
__global__ __launch_bounds__(256) void score_weights(
    const unsigned short* __restrict__ qkv, const unsigned short* __restrict__ gw,
    unsigned short* __restrict__ Wout, float* __restrict__ L,
    const float* __restrict__ alpha)
{
  const int tid  = threadIdx.x;
  const int lane = tid & 63;
  const int wave = tid >> 6;
  const int wr = wave >> 1, wc = wave & 1;
  const int n0 = blockIdx.x * 128;
  const int m0 = blockIdx.y * 128;
  const int b  = blockIdx.z;

  const int l15 = lane & 15;
  const int q   = lane >> 4;
  const int q8  = q * 8;

  // ---- group phase: direct-from-global frags, K=64 (cols 49..63 zero) ----
  const unsigned short* gq = gw + ((long long)(b * 1024 + m0 + wr * 64)) * 64;
  const unsigned short* gk = gw + ((long long)(b * 1024 + n0 + wc * 64)) * 64;
  floatx4 gacc[4][4];
#pragma unroll
  for (int i = 0; i < 4; ++i)
#pragma unroll
    for (int j = 0; j < 4; ++j) gacc[i][j] = floatx4{0.f, 0.f, 0.f, 0.f};
#pragma unroll
  for (int ks = 0; ks < 2; ++ks) {
    short8 af[4], bfv[4];
#pragma unroll
    for (int i = 0; i < 4; ++i) af[i]  = *(const short8*)&gq[(long long)(i * 16 + l15) * 64 + ks * 32 + q8];
#pragma unroll
    for (int j = 0; j < 4; ++j) bfv[j] = *(const short8*)&gk[(long long)(j * 16 + l15) * 64 + ks * 32 + q8];
#pragma unroll
    for (int i = 0; i < 4; ++i)
#pragma unroll
      for (int j = 0; j < 4; ++j)
        gacc[i][j] = __builtin_amdgcn_mfma_f32_16x16x32_bf16(bfv[j], af[i], gacc[i][j], 0, 0, 0);
  }
  const float aa    = 1.0f / (1.0f + __expf(-alpha[0]));
  const float onema = 1.0f - aa;
  half2v gfp[4][4][2];
#pragma unroll
  for (int i = 0; i < 4; ++i)
#pragma unroll
    for (int j = 0; j < 4; ++j) {
      gfp[i][j][0] = half2v{(_Float16)(aa + onema * gacc[i][j][0]),
                            (_Float16)(aa + onema * gacc[i][j][1])};
      gfp[i][j][1] = half2v{(_Float16)(aa + onema * gacc[i][j][2]),
                            (_Float16)(aa + onema * gacc[i][j][3])};
    }

  // ---- QK^T loop, BK=32 paired-row swizzle ----
  const unsigned short* Aq = qkv + ((long long)(b * 1024 + m0)) * 2304;        // q cols 0..767
  const unsigned short* Bk = qkv + ((long long)(b * 1024 + n0)) * 2304 + 768;  // k cols 768..1535

  __shared__ unsigned short As[128 * 32];
  __shared__ unsigned short Bs[128 * 32];

  floatx4 sacc[4][4];
#pragma unroll
  for (int i = 0; i < 4; ++i)
#pragma unroll
    for (int j = 0; j < 4; ++j) sacc[i][j] = floatx4{0.f, 0.f, 0.f, 0.f};

  const int t    = (lane & 7) ^ (lane >> 3);
  const int srow = 2 * (lane >> 3) + (t >> 2);
  const int scol = (t & 3) * 8;
  const unsigned short* ga0 = Aq + (long long)(wave * 32 + srow) * 2304 + scol;
  const unsigned short* ga1 = ga0 + 16LL * 2304;
  const unsigned short* gb0 = Bk + (long long)(wave * 32 + srow) * 2304 + scol;
  const unsigned short* gb1 = gb0 + 16LL * 2304;
  unsigned short* lA0 = As + wave * 1024;
  unsigned short* lA1 = lA0 + 512;
  unsigned short* lB0 = Bs + wave * 1024;
  unsigned short* lB1 = lB0 + 512;

  const int rofs = (l15 >> 1) * 64 + (((q + 4 * (l15 & 1)) ^ (l15 >> 1)) * 8);

  for (int kt = 0; kt < 768; kt += 32) {
    __syncthreads();
    stage16(ga0 + kt, lA0);
    stage16(ga1 + kt, lA1);
    stage16(gb0 + kt, lB0);
    stage16(gb1 + kt, lB1);
    __syncthreads();
    short8 af[4], bfv[4];
#pragma unroll
    for (int i = 0; i < 4; ++i) af[i]  = *(const short8*)&As[(wr * 32 + i * 8) * 64 + rofs];
#pragma unroll
    for (int j = 0; j < 4; ++j) bfv[j] = *(const short8*)&Bs[(wc * 32 + j * 8) * 64 + rofs];
#pragma unroll
    for (int i = 0; i < 4; ++i)
#pragma unroll
      for (int j = 0; j < 4; ++j)
        sacc[i][j] = __builtin_amdgcn_mfma_f32_16x16x32_bf16(bfv[j], af[i], sacc[i][j], 0, 0, 0);
  }

  const float scale = 0.03608439182435161f;  // 768^-0.5
  unsigned short* Wb = Wout + ((long long)b << 20);

#pragma unroll
  for (int i = 0; i < 4; ++i) {
    const int row = m0 + wr * 64 + i * 16 + l15;
    float ls = 0.0f;
#pragma unroll
    for (int j = 0; j < 4; ++j) {
      const int colb = n0 + wc * 64 + j * 16 + q * 4;
      float e0 = __expf(sacc[i][j][0] * scale);
      float e1 = __expf(sacc[i][j][1] * scale);
      float e2 = __expf(sacc[i][j][2] * scale);
      float e3 = __expf(sacc[i][j][3] * scale);
      ls += (e0 + e1) + (e2 + e3);
      *(short4v*)&Wb[(long long)row * 1024 + colb] =
        pack4(e0 * (float)gfp[i][j][0][0], e1 * (float)gfp[i][j][0][1],
              e2 * (float)gfp[i][j][1][0], e3 * (float)gfp[i][j][1][1]);
    }
    ls += __shfl_xor(ls, 16, 64);
    ls += __shfl_xor(ls, 32, 64);
    if (lane < 16) atomicAdd(&L[b * 1024 + row], ls);
  }
}

// gw[row][0..63] = softmax(q_row @ W_gp) padded with zeros (cols 49..63).
__global__ __launch_bounds__(256) void gw_kernel(
    const unsigned short* __restrict__ qkv, const unsigned short* __restrict__ WgpT,
    unsigned short* __restrict__ gw)
{
  const int wave = threadIdx.x >> 6;
  const int lane = threadIdx.x & 63;
  const long long row = (long long)blockIdx.x * 4 + wave;
  const unsigned short* q = qkv + row * 2304;
  float qv[12];
#pragma unroll
  for (int j = 0; j < 12; ++j) qv[j] = b2f(q[lane + 64 * j]);

  float logit = -1e30f;
  for (int g = 0; g < 49; ++g) {
    const unsigned short* wg = WgpT + g * 768;
    float acc = 0.0f;
#pragma unroll
    for (int j = 0; j < 12; ++j) acc += qv[j] * b2f(wg[lane + 64 * j]);
#pragma unroll
    for (int m = 1; m < 64; m <<= 1) acc += __shfl_xor(acc, m, 64);
    if (lane == g) logit = acc;
  }
  float mx = logit;
#pragma unroll
  for (int m = 1; m < 64; m <<= 1) mx = fmaxf(mx, __shfl_xor(mx, m, 64));
  const float e = (lane < 49) ? __expf(logit - mx) : 0.0f;
  float s = e;
#pragma unroll
  for (int m = 1; m < 64; m <<= 1) s += __shfl_xor(s, m, 64);
  gw[row * 64 + lane] = f2b(e / s);
}

__global__ void convert_f2b(const float* __restrict__ in, unsigned short* __restrict__ out, long long n)
{
  long long i = ((long long)blockIdx.x * 256 + threadIdx.x) * 4;
  if (i + 3 >= n) {
    for (long long k = i; k < n; ++k) out[k] = f2b(in[k]);
    return;
  }
  float4 v = *(const float4*)(in + i);
  out[i + 0] = f2b(v.x);
  out[i + 1] = f2b(v.y);
  out[i + 2] = f2b(v.z);
  out[i + 3] = f2b(v.w);
}

__global__ void transpose_f2b(const float* __restrict__ in, unsigned short* __restrict__ out,
                              int R, int C, int ldin, int ldout)
{
  __shared__ unsigned short t[32][33];
  const int c0 = blockIdx.x * 32, r0 = blockIdx.y * 32;
  for (int i = threadIdx.y; i < 32; i += 8) {
    const int r = r0 + i, c = c0 + threadIdx.x;
    if (r < R && c < C) t[i][threadIdx.x] = f2b(in[(long long)r * ldin + c]);
  }
  __syncthreads();
  for (int i = threadIdx.y; i < 32; i += 8) {
    const int r = c0 + i, c = r0 + threadIdx.x;
    if (r < C && c < R) out[(long long)r * ldout + c] = t[threadIdx.x][i];
  }
}

__global__ void transpose_bf16(const unsigned short* __restrict__ in, unsigned short* __restrict__ out,
                               int R, int C, int ldin, int ldout, long long sIn, long long sOut)
{
  __shared__ unsigned short t[32][33];
  in  += (long long)blockIdx.z * sIn;
  out += (long long)blockIdx.z * sOut;
  const int c0 = blockIdx.x * 32, r0 = blockIdx.y * 32;
  for (int i = threadIdx.y; i < 32; i += 8) {
    const int r = r0 + i, c = c0 + threadIdx.x;
    if (r < R && c < C) t[i][threadIdx.x] = in[(long long)r * ldin + c];
  }
  __syncthreads();
  for (int i = threadIdx.y; i < 32; i += 8) {
    const int r = c0 + i, c = r0 + threadIdx.x;
    if (r < C && c < R) out[(long long)r * ldout + c] = t[threadIdx.x][i];
  }
}

extern "C" void kernel_launch(void* const* d_in, const int* in_sizes, int n_in,
                              void* d_out, int out_size, void* d_ws, size_t ws_size,
                              hipStream_t stream)
{
  const float* x      = (const float*)d_in[0];
  const float* W_qkv  = (const float*)d_in[1];
  const float* b_qkv  = (const float*)d_in[2];
  const float* W_proj = (const float*)d_in[3];
  const float* b_proj = (const float*)d_in[4];
  const float* W_gp   = (const float*)d_in[5];
  const float* alpha  = (const float*)d_in[6];

  char* p = (char*)d_ws;
  auto alloc = [&](size_t bytes) { char* r = p; p += (bytes + 255) & ~255ULL; return r; };
  unsigned short* qkv    = (unsigned short*)alloc(16384ULL * 2304 * 2);   // q|k|v interleaved rows
  unsigned short* xb     = (unsigned short*)alloc(16384ULL * 768 * 2);
  unsigned short* WqkvT  = (unsigned short*)alloc(2304ULL * 768 * 2);
  unsigned short* WprojT = (unsigned short*)alloc(768ULL * 768 * 2);
  unsigned short* WgpT   = (unsigned short*)alloc(49ULL * 768 * 2);
  unsigned short* gwbuf  = (unsigned short*)alloc(16384ULL * 64 * 2);
  float*          Lbuf   = (float*)alloc(16384ULL * 4);
  unsigned short* wmat   = (unsigned short*)alloc(16ULL * 1024 * 1024 * 2);
  unsigned short* vT     = (unsigned short*)alloc(16ULL * 768 * 1024 * 2);

  const dim3 blk256(256);
  const dim3 tb(32, 8);

  // input conversions / transposes (fp32 -> bf16)
  convert_f2b<<<dim3(12288), blk256, 0, stream>>>(x, xb, 16384LL * 768);
  transpose_f2b<<<dim3(72, 24), tb, 0, stream>>>(W_qkv, WqkvT, 768, 2304, 2304, 768);
  transpose_f2b<<<dim3(24, 24), tb, 0, stream>>>(W_proj, WprojT, 768, 768, 768, 768);
  transpose_f2b<<<dim3(2, 24), tb, 0, stream>>>(W_gp, WgpT, 768, 49, 49, 768);

  // qkv = x @ W_qkv + b_qkv   (M=16384, N=2304, K=768), bf16 out
  gemm_bt<0><<<dim3(18, 128, 1), blk256, 0, stream>>>(xb, WqkvT, qkv, (float*)0, (const float*)0, b_qkv,
                                                      768, 768, 768, 2304, 0, 0, 0, 0);

  // vT[b][768][1024] = v^T (v = qkv cols 1536..2303)
  transpose_bf16<<<dim3(24, 32, 16), tb, 0, stream>>>(qkv + 1536, vT, 1024, 768, 2304, 1024,
                                                      1024LL * 2304, 768LL * 1024);

  // gw = softmax(q @ W_gp), padded to 64
  gw_kernel<<<dim3(4096), blk256, 0, stream>>>(qkv, WgpT, gwbuf);

  hipMemsetAsync(Lbuf, 0, 16384 * 4, stream);

  // weights (unnormalized) + L
  score_weights<<<dim3(8, 8, 16), blk256, 0, stream>>>(qkv, gwbuf, wmat, Lbuf, alpha);

  // attn_out = (weights @ v) / L  -> written into qkv's dead k-columns (bf16)
  gemm_bt<1><<<dim3(6, 8, 16), blk256, 0, stream>>>(wmat, vT, qkv + 768, (float*)0, Lbuf, (const float*)0,
                                                    1024, 1024, 1024, 2304,
                                                    1024LL * 1024, 768LL * 1024, 1024LL * 2304, 1024);

  // out = attn_out @ W_proj + b_proj  (fp32 out)
  gemm_bt<2><<<dim3(6, 128, 1), blk256, 0, stream>>>(qkv + 768, WprojT, (unsigned short*)0, (float*)d_out,
                                                     (const float*)0, b_proj,
                                                     768, 2304, 768, 768, 0, 0, 0, 0);
}

// Round 6
// 445.652 us; speedup vs baseline: 1.2069x; 1.0397x over previous
//
#include <hip/hip_runtime.h>
#include <stdint.h>

typedef __attribute__((ext_vector_type(8))) short short8;
typedef __attribute__((ext_vector_type(4))) short short4v;
typedef __attribute__((ext_vector_type(4))) float floatx4;
typedef _Float16 half2v __attribute__((ext_vector_type(2)));

__device__ __forceinline__ float b2f(unsigned short u) {
  union { unsigned int i; float f; } v; v.i = ((unsigned int)u) << 16; return v.f;
}
__device__ __forceinline__ unsigned short f2b(float f) {
  union { float f; unsigned int i; } v; v.f = f;
  unsigned int i = v.i;
  return (unsigned short)((i + 0x7FFFu + ((i >> 16) & 1u)) >> 16);
}
__device__ __forceinline__ short4v pack4(float a, float b, float c, float d) {
  short4v r;
  r[0] = (short)f2b(a); r[1] = (short)f2b(b); r[2] = (short)f2b(c); r[3] = (short)f2b(d);
  return r;
}

// global -> LDS 16B per lane. lds_base wave-uniform; HW adds lane*16B.
__device__ __forceinline__ void stage16(const unsigned short* g, unsigned short* lds_base) {
  __builtin_amdgcn_global_load_lds((__attribute__((address_space(1))) const unsigned int*)g,
                                   (__attribute__((address_space(3))) unsigned int*)lds_base,
                                   16, 0, 0);
}

// ---------------------------------------------------------------------------
// BK=32 gemm core with paired-row LDS swizzle (verified 0 bank conflicts, r5).
// __launch_bounds__(256,4): cap unified VGPR+AGPR at 128 -> 4 blocks/CU.
// MFMA operands swapped (B-frag first): C rows on lanes, 4 consecutive cols
// per lane -> 8-B packed stores.
// WRITE_VT: for col-tiles >=1536 (v-range), write ONLY the transposed tile
// into vT (fused V-transpose; nothing reads v in normal layout).
// ---------------------------------------------------------------------------
template<int WRITE_VT>
__global__ __launch_bounds__(256, 4) void gemm_bt(
    const unsigned short* __restrict__ A, const unsigned short* __restrict__ B,
    unsigned short* __restrict__ Cb, float* __restrict__ Cf,
    unsigned short* __restrict__ vT,
    const float* __restrict__ rowdiv, const float* __restrict__ bias,
    int K, int lda, int ldb, int ldc,
    long long sA, long long sB, long long sC, long long sRD)
{
  const int tid  = threadIdx.x;
  const int lane = tid & 63;
  const int wave = tid >> 6;
  const int wr = wave >> 1, wc = wave & 1;
  const int m0 = blockIdx.y * 128;
  const int n0 = blockIdx.x * 128;
  const int bz = blockIdx.z;
  A += (long long)bz * sA;
  B += (long long)bz * sB;
  const float* rd = rowdiv ? rowdiv + (long long)bz * sRD : (const float*)0;

  __shared__ unsigned short As[128 * 32];
  __shared__ unsigned short Bs[128 * 32];

  floatx4 acc[4][4];
#pragma unroll
  for (int i = 0; i < 4; ++i)
#pragma unroll
    for (int j = 0; j < 4; ++j) acc[i][j] = floatx4{0.f, 0.f, 0.f, 0.f};

  // staging source map: lane l -> physical (P=l>>3, p=l&7); t=p^(l>>3);
  // source row_local = 2*(l>>3)+(t>>2), chunk = t&3.
  const int t    = (lane & 7) ^ (lane >> 3);
  const int srow = 2 * (lane >> 3) + (t >> 2);
  const int scol = (t & 3) * 8;
  const unsigned short* ga0 = A + (long long)(m0 + wave * 32 + srow) * lda + scol;
  const unsigned short* ga1 = ga0 + 16LL * lda;
  const unsigned short* gb0 = B + (long long)(n0 + wave * 32 + srow) * ldb + scol;
  const unsigned short* gb1 = gb0 + 16LL * ldb;
  unsigned short* lA0 = As + wave * 1024;
  unsigned short* lA1 = lA0 + 512;
  unsigned short* lB0 = Bs + wave * 1024;
  unsigned short* lB1 = lB0 + 512;

  const int l15  = lane & 15;
  const int q    = lane >> 4;
  const int rofs = (l15 >> 1) * 64 + (((q + 4 * (l15 & 1)) ^ (l15 >> 1)) * 8);

  for (int kt = 0; kt < K; kt += 32) {
    __syncthreads();
    stage16(ga0 + kt, lA0);
    stage16(ga1 + kt, lA1);
    stage16(gb0 + kt, lB0);
    stage16(gb1 + kt, lB1);
    __syncthreads();
    short8 af[4], bfv[4];
#pragma unroll
    for (int i = 0; i < 4; ++i) af[i]  = *(const short8*)&As[(wr * 32 + i * 8) * 64 + rofs];
#pragma unroll
    for (int j = 0; j < 4; ++j) bfv[j] = *(const short8*)&Bs[(wc * 32 + j * 8) * 64 + rofs];
#pragma unroll
    for (int i = 0; i < 4; ++i)
#pragma unroll
      for (int j = 0; j < 4; ++j)
        acc[i][j] = __builtin_amdgcn_mfma_f32_16x16x32_bf16(bfv[j], af[i], acc[i][j], 0, 0, 0);
  }

  // Epilogue: lane holds C[row=m0+wr*64+i*16+l15][cols n0+wc*64+j*16+q*4 .. +3]
  if (WRITE_VT && n0 >= 1536) {
    // v-range tile: write transposed into vT[batch][768][1024] only.
    unsigned short* vTb = vT + (long long)(m0 >> 10) * (768LL * 1024);
#pragma unroll
    for (int i = 0; i < 4; ++i) {
      const int rowl = (m0 & 1023) + wr * 64 + i * 16 + l15;
#pragma unroll
      for (int j = 0; j < 4; ++j) {
        const int colb = n0 - 1536 + wc * 64 + j * 16 + q * 4;
        const float4 bi = *(const float4*)&bias[colb + 1536];
        floatx4 v = acc[i][j];
        vTb[(long long)(colb + 0) * 1024 + rowl] = f2b(v[0] + bi.x);
        vTb[(long long)(colb + 1) * 1024 + rowl] = f2b(v[1] + bi.y);
        vTb[(long long)(colb + 2) * 1024 + rowl] = f2b(v[2] + bi.z);
        vTb[(long long)(colb + 3) * 1024 + rowl] = f2b(v[3] + bi.w);
      }
    }
    return;
  }
#pragma unroll
  for (int i = 0; i < 4; ++i) {
    const int row = m0 + wr * 64 + i * 16 + l15;
    const float rcp = rd ? __builtin_amdgcn_rcpf(rd[row]) : 1.0f;
#pragma unroll
    for (int j = 0; j < 4; ++j) {
      const int colb = n0 + wc * 64 + j * 16 + q * 4;
      floatx4 v = acc[i][j];
      if (rd) { v[0] *= rcp; v[1] *= rcp; v[2] *= rcp; v[3] *= rcp; }
      if (bias) {
        const float4 bi = *(const float4*)&bias[colb];
        v[0] += bi.x; v[1] += bi.y; v[2] += bi.z; v[3] += bi.w;
      }
      if (Cb) *(short4v*)&Cb[(long long)bz * sC + (long long)row * ldc + colb] = pack4(v[0], v[1], v[2], v[3]);
      else    *(floatx4*)&Cf[(long long)bz * sC + (long long)row * ldc + colb] = v;
    }
  }
}

// ---------------------------------------------------------------------------
// Fused scores + group + exp, paired-row swizzle in the QK^T loop.
// W[b][m][n] = exp(q.k*scale) * (a + (1-a)*gw_m.gw_n);  L[row] += sum exp.
// ---------------------------------------------------------------------------
__global__ __launch_bounds__(256) void score_weights(
    const unsigned short* __restrict__ qkv, const unsigned short* __restrict__ gw,
    unsigned short* __restrict__ Wout, float* __restrict__ L,
    const float* __restrict__ alpha)
{
  const int tid  = threadIdx.x;
  const int lane = tid & 63;
  const int wave = tid >> 6;
  const int wr = wave >> 1, wc = wave & 1;
  const int n0 = blockIdx.x * 128;
  const int m0 = blockIdx.y * 128;
  const int b  = blockIdx.z;

  const int l15 = lane & 15;
  const int q   = lane >> 4;
  const int q8  = q * 8;

  // ---- group phase: direct-from-global frags, K=64 (cols 49..63 zero) ----
  const unsigned short* gq = gw + ((long long)(b * 1024 + m0 + wr * 64)) * 64;
  const unsigned short* gk = gw + ((long long)(b * 1024 + n0 + wc * 64)) * 64;
  floatx4 gacc[4][4];
#pragma unroll
  for (int i = 0; i < 4; ++i)
#pragma unroll
    for (int j = 0; j < 4; ++j) gacc[i][j] = floatx4{0.f, 0.f, 0.f, 0.f};
#pragma unroll
  for (int ks = 0; ks < 2; ++ks) {
    short8 af[4], bfv[4];
#pragma unroll
    for (int i = 0; i < 4; ++i) af[i]  = *(const short8*)&gq[(long long)(i * 16 + l15) * 64 + ks * 32 + q8];
#pragma unroll
    for (int j = 0; j < 4; ++j) bfv[j] = *(const short8*)&gk[(long long)(j * 16 + l15) * 64 + ks * 32 + q8];
#pragma unroll
    for (int i = 0; i < 4; ++i)
#pragma unroll
      for (int j = 0; j < 4; ++j)
        gacc[i][j] = __builtin_amdgcn_mfma_f32_16x16x32_bf16(bfv[j], af[i], gacc[i][j], 0, 0, 0);
  }
  const float aa    = 1.0f / (1.0f + __expf(-alpha[0]));
  const float onema = 1.0f - aa;
  half2v gfp[4][4][2];
#pragma unroll
  for (int i = 0; i < 4; ++i)
#pragma unroll
    for (int j = 0; j < 4; ++j) {
      gfp[i][j][0] = half2v{(_Float16)(aa + onema * gacc[i][j][0]),
                            (_Float16)(aa + onema * gacc[i][j][1])};
      gfp[i][j][1] = half2v{(_Float16)(aa + onema * gacc[i][j][2]),
                            (_Float16)(aa + onema * gacc[i][j][3])};
    }

  // ---- QK^T loop, BK=32 paired-row swizzle ----
  const unsigned short* Aq = qkv + ((long long)(b * 1024 + m0)) * 2304;        // q cols 0..767
  const unsigned short* Bk = qkv + ((long long)(b * 1024 + n0)) * 2304 + 768;  // k cols 768..1535

  __shared__ unsigned short As[128 * 32];
  __shared__ unsigned short Bs[128 * 32];

  floatx4 sacc[4][4];
#pragma unroll
  for (int i = 0; i < 4; ++i)
#pragma unroll
    for (int j = 0; j < 4; ++j) sacc[i][j] = floatx4{0.f, 0.f, 0.f, 0.f};

  const int t    = (lane & 7) ^ (lane >> 3);
  const int srow = 2 * (lane >> 3) + (t >> 2);
  const int scol = (t & 3) * 8;
  const unsigned short* ga0 = Aq + (long long)(wave * 32 + srow) * 2304 + scol;
  const unsigned short* ga1 = ga0 + 16LL * 2304;
  const unsigned short* gb0 = Bk + (long long)(wave * 32 + srow) * 2304 + scol;
  const unsigned short* gb1 = gb0 + 16LL * 2304;
  unsigned short* lA0 = As + wave * 1024;
  unsigned short* lA1 = lA0 + 512;
  unsigned short* lB0 = Bs + wave * 1024;
  unsigned short* lB1 = lB0 + 512;

  const int rofs = (l15 >> 1) * 64 + (((q + 4 * (l15 & 1)) ^ (l15 >> 1)) * 8);

  for (int kt = 0; kt < 768; kt += 32) {
    __syncthreads();
    stage16(ga0 + kt, lA0);
    stage16(ga1 + kt, lA1);
    stage16(gb0 + kt, lB0);
    stage16(gb1 + kt, lB1);
    __syncthreads();
    short8 af[4], bfv[4];
#pragma unroll
    for (int i = 0; i < 4; ++i) af[i]  = *(const short8*)&As[(wr * 32 + i * 8) * 64 + rofs];
#pragma unroll
    for (int j = 0; j < 4; ++j) bfv[j] = *(const short8*)&Bs[(wc * 32 + j * 8) * 64 + rofs];
#pragma unroll
    for (int i = 0; i < 4; ++i)
#pragma unroll
      for (int j = 0; j < 4; ++j)
        sacc[i][j] = __builtin_amdgcn_mfma_f32_16x16x32_bf16(bfv[j], af[i], sacc[i][j], 0, 0, 0);
  }

  const float scale = 0.03608439182435161f;  // 768^-0.5
  unsigned short* Wb = Wout + ((long long)b << 20);

#pragma unroll
  for (int i = 0; i < 4; ++i) {
    const int row = m0 + wr * 64 + i * 16 + l15;
    float ls = 0.0f;
#pragma unroll
    for (int j = 0; j < 4; ++j) {
      const int colb = n0 + wc * 64 + j * 16 + q * 4;
      float e0 = __expf(sacc[i][j][0] * scale);
      float e1 = __expf(sacc[i][j][1] * scale);
      float e2 = __expf(sacc[i][j][2] * scale);
      float e3 = __expf(sacc[i][j][3] * scale);
      ls += (e0 + e1) + (e2 + e3);
      *(short4v*)&Wb[(long long)row * 1024 + colb] =
        pack4(e0 * (float)gfp[i][j][0][0], e1 * (float)gfp[i][j][0][1],
              e2 * (float)gfp[i][j][1][0], e3 * (float)gfp[i][j][1][1]);
    }
    ls += __shfl_xor(ls, 16, 64);
    ls += __shfl_xor(ls, 32, 64);
    if (lane < 16) atomicAdd(&L[b * 1024 + row], ls);
  }
}

// gw[row][0..63] = softmax(q_row @ W_gp) padded with zeros (cols 49..63).
__global__ __launch_bounds__(256) void gw_kernel(
    const unsigned short* __restrict__ qkv, const unsigned short* __restrict__ WgpT,
    unsigned short* __restrict__ gw)
{
  const int wave = threadIdx.x >> 6;
  const int lane = threadIdx.x & 63;
  const long long row = (long long)blockIdx.x * 4 + wave;
  const unsigned short* q = qkv + row * 2304;
  float qv[12];
#pragma unroll
  for (int j = 0; j < 12; ++j) qv[j] = b2f(q[lane + 64 * j]);

  float logit = -1e30f;
  for (int g = 0; g < 49; ++g) {
    const unsigned short* wg = WgpT + g * 768;
    float acc = 0.0f;
#pragma unroll
    for (int j = 0; j < 12; ++j) acc += qv[j] * b2f(wg[lane + 64 * j]);
#pragma unroll
    for (int m = 1; m < 64; m <<= 1) acc += __shfl_xor(acc, m, 64);
    if (lane == g) logit = acc;
  }
  float mx = logit;
#pragma unroll
  for (int m = 1; m < 64; m <<= 1) mx = fmaxf(mx, __shfl_xor(mx, m, 64));
  const float e = (lane < 49) ? __expf(logit - mx) : 0.0f;
  float s = e;
#pragma unroll
  for (int m = 1; m < 64; m <<= 1) s += __shfl_xor(s, m, 64);
  gw[row * 64 + lane] = f2b(e / s);
}

__global__ void convert_f2b(const float* __restrict__ in, unsigned short* __restrict__ out, long long n)
{
  long long i = ((long long)blockIdx.x * 256 + threadIdx.x) * 4;
  if (i + 3 >= n) {
    for (long long k = i; k < n; ++k) out[k] = f2b(in[k]);
    return;
  }
  float4 v = *(const float4*)(in + i);
  out[i + 0] = f2b(v.x);
  out[i + 1] = f2b(v.y);
  out[i + 2] = f2b(v.z);
  out[i + 3] = f2b(v.w);
}

__global__ void transpose_f2b(const float* __restrict__ in, unsigned short* __restrict__ out,
                              int R, int C, int ldin, int ldout)
{
  __shared__ unsigned short t[32][33];
  const int c0 = blockIdx.x * 32, r0 = blockIdx.y * 32;
  for (int i = threadIdx.y; i < 32; i += 8) {
    const int r = r0 + i, c = c0 + threadIdx.x;
    if (r < R && c < C) t[i][threadIdx.x] = f2b(in[(long long)r * ldin + c]);
  }
  __syncthreads();
  for (int i = threadIdx.y; i < 32; i += 8) {
    const int r = c0 + i, c = r0 + threadIdx.x;
    if (r < C && c < R) out[(long long)r * ldout + c] = t[threadIdx.x][i];
  }
}

extern "C" void kernel_launch(void* const* d_in, const int* in_sizes, int n_in,
                              void* d_out, int out_size, void* d_ws, size_t ws_size,
                              hipStream_t stream)
{
  const float* x      = (const float*)d_in[0];
  const float* W_qkv  = (const float*)d_in[1];
  const float* b_qkv  = (const float*)d_in[2];
  const float* W_proj = (const float*)d_in[3];
  const float* b_proj = (const float*)d_in[4];
  const float* W_gp   = (const float*)d_in[5];
  const float* alpha  = (const float*)d_in[6];

  char* p = (char*)d_ws;
  auto alloc = [&](size_t bytes) { char* r = p; p += (bytes + 255) & ~255ULL; return r; };
  unsigned short* qkv    = (unsigned short*)alloc(16384ULL * 2304 * 2);   // q|k rows (v goes to vT)
  unsigned short* xb     = (unsigned short*)alloc(16384ULL * 768 * 2);
  unsigned short* WqkvT  = (unsigned short*)alloc(2304ULL * 768 * 2);
  unsigned short* WprojT = (unsigned short*)alloc(768ULL * 768 * 2);
  unsigned short* WgpT   = (unsigned short*)alloc(49ULL * 768 * 2);
  unsigned short* gwbuf  = (unsigned short*)alloc(16384ULL * 64 * 2);
  float*          Lbuf   = (float*)alloc(16384ULL * 4);
  unsigned short* wmat   = (unsigned short*)alloc(16ULL * 1024 * 1024 * 2);
  unsigned short* vT     = (unsigned short*)alloc(16ULL * 768 * 1024 * 2);

  const dim3 blk256(256);
  const dim3 tb(32, 8);

  // input conversions / transposes (fp32 -> bf16)
  convert_f2b<<<dim3(12288), blk256, 0, stream>>>(x, xb, 16384LL * 768);
  transpose_f2b<<<dim3(72, 24), tb, 0, stream>>>(W_qkv, WqkvT, 768, 2304, 2304, 768);
  transpose_f2b<<<dim3(24, 24), tb, 0, stream>>>(W_proj, WprojT, 768, 768, 768, 768);
  transpose_f2b<<<dim3(2, 24), tb, 0, stream>>>(W_gp, WgpT, 768, 49, 49, 768);

  // qkv = x @ W_qkv + b_qkv; q,k cols normal into qkv; v cols transposed into vT
  gemm_bt<1><<<dim3(18, 128, 1), blk256, 0, stream>>>(xb, WqkvT, qkv, (float*)0, vT,
                                                      (const float*)0, b_qkv,
                                                      768, 768, 768, 2304, 0, 0, 0, 0);

  // gw = softmax(q @ W_gp), padded to 64
  gw_kernel<<<dim3(4096), blk256, 0, stream>>>(qkv, WgpT, gwbuf);

  hipMemsetAsync(Lbuf, 0, 16384 * 4, stream);

  // weights (unnormalized) + L
  score_weights<<<dim3(8, 8, 16), blk256, 0, stream>>>(qkv, gwbuf, wmat, Lbuf, alpha);

  // attn_out = (weights @ v) / L  -> written into qkv's dead k-columns (bf16)
  gemm_bt<0><<<dim3(6, 8, 16), blk256, 0, stream>>>(wmat, vT, qkv + 768, (float*)0, (unsigned short*)0,
                                                    Lbuf, (const float*)0,
                                                    1024, 1024, 1024, 2304,
                                                    1024LL * 1024, 768LL * 1024, 1024LL * 2304, 1024);

  // out = attn_out @ W_proj + b_proj  (fp32 out)
  gemm_bt<0><<<dim3(6, 128, 1), blk256, 0, stream>>>(qkv + 768, WprojT, (unsigned short*)0, (float*)d_out,
                                                     (unsigned short*)0, (const float*)0, b_proj,
                                                     768, 2304, 768, 768, 0, 0, 0, 0);
}

// Round 7
// 432.356 us; speedup vs baseline: 1.2440x; 1.0308x over previous
//
#include <hip/hip_runtime.h>
#include <stdint.h>

typedef __attribute__((ext_vector_type(8))) short short8;
typedef __attribute__((ext_vector_type(4))) short short4v;
typedef __attribute__((ext_vector_type(4))) float floatx4;
typedef _Float16 half2v __attribute__((ext_vector_type(2)));

__device__ __forceinline__ float b2f(unsigned short u) {
  union { unsigned int i; float f; } v; v.i = ((unsigned int)u) << 16; return v.f;
}
__device__ __forceinline__ unsigned short f2b(float f) {
  union { float f; unsigned int i; } v; v.f = f;
  unsigned int i = v.i;
  return (unsigned short)((i + 0x7FFFu + ((i >> 16) & 1u)) >> 16);
}
__device__ __forceinline__ short4v pack4(float a, float b, float c, float d) {
  short4v r;
  r[0] = (short)f2b(a); r[1] = (short)f2b(b); r[2] = (short)f2b(c); r[3] = (short)f2b(d);
  return r;
}

// global -> LDS 16B per lane. lds_base wave-uniform; HW adds lane*16B.
__device__ __forceinline__ void stage16(const unsigned short* g, unsigned short* lds_base) {
  __builtin_amdgcn_global_load_lds((__attribute__((address_space(1))) const unsigned int*)g,
                                   (__attribute__((address_space(3))) unsigned int*)lds_base,
                                   16, 0, 0);
}

// ---------------------------------------------------------------------------
// BK=32 gemm core, paired-row LDS swizzle (0 bank conflicts, r5),
// swapped-operand MFMA (C rows on lanes -> 8-B packed stores),
// __launch_bounds__(256,4).
// SWZ=1: 1-D grid 2304 = 8 XCD * 16 ytiles * 18 xtiles; each XCD owns 16
// contiguous y-tiles so its A-tiles live in its own L2 (L2s not shared).
// ---------------------------------------------------------------------------
template<int SWZ>
__global__ __launch_bounds__(256, 4) void gemm_bt(
    const unsigned short* __restrict__ A, const unsigned short* __restrict__ B,
    unsigned short* __restrict__ Cb, float* __restrict__ Cf,
    const float* __restrict__ rowdiv, const float* __restrict__ bias,
    int K, int lda, int ldb, int ldc,
    long long sA, long long sB, long long sC, long long sRD)
{
  const int tid  = threadIdx.x;
  const int lane = tid & 63;
  const int wave = tid >> 6;
  const int wr = wave >> 1, wc = wave & 1;
  int m0, n0;
  if (SWZ) {
    const int lin  = blockIdx.x;
    const int xcd  = lin & 7;
    const int rem  = lin >> 3;        // 0..287
    const int yloc = rem / 18;
    const int x    = rem - yloc * 18;
    m0 = (xcd * 16 + yloc) * 128;
    n0 = x * 128;
  } else {
    m0 = blockIdx.y * 128;
    n0 = blockIdx.x * 128;
  }
  const int bz = blockIdx.z;
  A += (long long)bz * sA;
  B += (long long)bz * sB;
  const float* rd = rowdiv ? rowdiv + (long long)bz * sRD : (const float*)0;

  __shared__ unsigned short As[128 * 32];
  __shared__ unsigned short Bs[128 * 32];

  floatx4 acc[4][4];
#pragma unroll
  for (int i = 0; i < 4; ++i)
#pragma unroll
    for (int j = 0; j < 4; ++j) acc[i][j] = floatx4{0.f, 0.f, 0.f, 0.f};

  // staging source map: lane l -> physical (P=l>>3, p=l&7); t=p^(l>>3);
  // source row_local = 2*(l>>3)+(t>>2), chunk = t&3.
  const int t    = (lane & 7) ^ (lane >> 3);
  const int srow = 2 * (lane >> 3) + (t >> 2);
  const int scol = (t & 3) * 8;
  const unsigned short* ga0 = A + (long long)(m0 + wave * 32 + srow) * lda + scol;
  const unsigned short* ga1 = ga0 + 16LL * lda;
  const unsigned short* gb0 = B + (long long)(n0 + wave * 32 + srow) * ldb + scol;
  const unsigned short* gb1 = gb0 + 16LL * ldb;
  unsigned short* lA0 = As + wave * 1024;
  unsigned short* lA1 = lA0 + 512;
  unsigned short* lB0 = Bs + wave * 1024;
  unsigned short* lB1 = lB0 + 512;

  const int l15  = lane & 15;
  const int q    = lane >> 4;
  const int rofs = (l15 >> 1) * 64 + (((q + 4 * (l15 & 1)) ^ (l15 >> 1)) * 8);

  for (int kt = 0; kt < K; kt += 32) {
    __syncthreads();
    stage16(ga0 + kt, lA0);
    stage16(ga1 + kt, lA1);
    stage16(gb0 + kt, lB0);
    stage16(gb1 + kt, lB1);
    __syncthreads();
    short8 af[4], bfv[4];
#pragma unroll
    for (int i = 0; i < 4; ++i) af[i]  = *(const short8*)&As[(wr * 32 + i * 8) * 64 + rofs];
#pragma unroll
    for (int j = 0; j < 4; ++j) bfv[j] = *(const short8*)&Bs[(wc * 32 + j * 8) * 64 + rofs];
#pragma unroll
    for (int i = 0; i < 4; ++i)
#pragma unroll
      for (int j = 0; j < 4; ++j)
        acc[i][j] = __builtin_amdgcn_mfma_f32_16x16x32_bf16(bfv[j], af[i], acc[i][j], 0, 0, 0);
  }

  // Epilogue: lane holds C[row=m0+wr*64+i*16+l15][cols n0+wc*64+j*16+q*4 .. +3]
#pragma unroll
  for (int i = 0; i < 4; ++i) {
    const int row = m0 + wr * 64 + i * 16 + l15;
    const float rcp = rd ? __builtin_amdgcn_rcpf(rd[row]) : 1.0f;
#pragma unroll
    for (int j = 0; j < 4; ++j) {
      const int colb = n0 + wc * 64 + j * 16 + q * 4;
      floatx4 v = acc[i][j];
      if (rd) { v[0] *= rcp; v[1] *= rcp; v[2] *= rcp; v[3] *= rcp; }
      if (bias) {
        const float4 bi = *(const float4*)&bias[colb];
        v[0] += bi.x; v[1] += bi.y; v[2] += bi.z; v[3] += bi.w;
      }
      if (Cb) *(short4v*)&Cb[(long long)bz * sC + (long long)row * ldc + colb] = pack4(v[0], v[1], v[2], v[3]);
      else    *(floatx4*)&Cf[(long long)bz * sC + (long long)row * ldc + colb] = v;
    }
  }
}

// ---------------------------------------------------------------------------
// Fused scores + group + exp, paired-row swizzle in the QK^T loop.
// W[b][m][n] = exp(q.k*scale) * (a + (1-a)*gw_m.gw_n);  L[row] += sum exp.
// ---------------------------------------------------------------------------
__global__ __launch_bounds__(256) void score_weights(
    const unsigned short* __restrict__ qkv, const unsigned short* __restrict__ gw,
    unsigned short* __restrict__ Wout, float* __restrict__ L,
    const float* __restrict__ alpha)
{
  const int tid  = threadIdx.x;
  const int lane = tid & 63;
  const int wave = tid >> 6;
  const int wr = wave >> 1, wc = wave & 1;
  const int n0 = blockIdx.x * 128;
  const int m0 = blockIdx.y * 128;
  const int b  = blockIdx.z;

  const int l15 = lane & 15;
  const int q   = lane >> 4;
  const int q8  = q * 8;

  // ---- group phase: direct-from-global frags, K=64 (cols 49..63 zero) ----
  const unsigned short* gq = gw + ((long long)(b * 1024 + m0 + wr * 64)) * 64;
  const unsigned short* gk = gw + ((long long)(b * 1024 + n0 + wc * 64)) * 64;
  floatx4 gacc[4][4];
#pragma unroll
  for (int i = 0; i < 4; ++i)
#pragma unroll
    for (int j = 0; j < 4; ++j) gacc[i][j] = floatx4{0.f, 0.f, 0.f, 0.f};
#pragma unroll
  for (int ks = 0; ks < 2; ++ks) {
    short8 af[4], bfv[4];
#pragma unroll
    for (int i = 0; i < 4; ++i) af[i]  = *(const short8*)&gq[(long long)(i * 16 + l15) * 64 + ks * 32 + q8];
#pragma unroll
    for (int j = 0; j < 4; ++j) bfv[j] = *(const short8*)&gk[(long long)(j * 16 + l15) * 64 + ks * 32 + q8];
#pragma unroll
    for (int i = 0; i < 4; ++i)
#pragma unroll
      for (int j = 0; j < 4; ++j)
        gacc[i][j] = __builtin_amdgcn_mfma_f32_16x16x32_bf16(bfv[j], af[i], gacc[i][j], 0, 0, 0);
  }
  const float aa    = 1.0f / (1.0f + __expf(-alpha[0]));
  const float onema = 1.0f - aa;
  half2v gfp[4][4][2];
#pragma unroll
  for (int i = 0; i < 4; ++i)
#pragma unroll
    for (int j = 0; j < 4; ++j) {
      gfp[i][j][0] = half2v{(_Float16)(aa + onema * gacc[i][j][0]),
                            (_Float16)(aa + onema * gacc[i][j][1])};
      gfp[i][j][1] = half2v{(_Float16)(aa + onema * gacc[i][j][2]),
                            (_Float16)(aa + onema * gacc[i][j][3])};
    }

  // ---- QK^T loop, BK=32 paired-row swizzle ----
  const unsigned short* Aq = qkv + ((long long)(b * 1024 + m0)) * 2304;        // q cols 0..767
  const unsigned short* Bk = qkv + ((long long)(b * 1024 + n0)) * 2304 + 768;  // k cols 768..1535

  __shared__ unsigned short As[128 * 32];
  __shared__ unsigned short Bs[128 * 32];

  floatx4 sacc[4][4];
#pragma unroll
  for (int i = 0; i < 4; ++i)
#pragma unroll
    for (int j = 0; j < 4; ++j) sacc[i][j] = floatx4{0.f, 0.f, 0.f, 0.f};

  const int t    = (lane & 7) ^ (lane >> 3);
  const int srow = 2 * (lane >> 3) + (t >> 2);
  const int scol = (t & 3) * 8;
  const unsigned short* ga0 = Aq + (long long)(wave * 32 + srow) * 2304 + scol;
  const unsigned short* ga1 = ga0 + 16LL * 2304;
  const unsigned short* gb0 = Bk + (long long)(wave * 32 + srow) * 2304 + scol;
  const unsigned short* gb1 = gb0 + 16LL * 2304;
  unsigned short* lA0 = As + wave * 1024;
  unsigned short* lA1 = lA0 + 512;
  unsigned short* lB0 = Bs + wave * 1024;
  unsigned short* lB1 = lB0 + 512;

  const int rofs = (l15 >> 1) * 64 + (((q + 4 * (l15 & 1)) ^ (l15 >> 1)) * 8);

  for (int kt = 0; kt < 768; kt += 32) {
    __syncthreads();
    stage16(ga0 + kt, lA0);
    stage16(ga1 + kt, lA1);
    stage16(gb0 + kt, lB0);
    stage16(gb1 + kt, lB1);
    __syncthreads();
    short8 af[4], bfv[4];
#pragma unroll
    for (int i = 0; i < 4; ++i) af[i]  = *(const short8*)&As[(wr * 32 + i * 8) * 64 + rofs];
#pragma unroll
    for (int j = 0; j < 4; ++j) bfv[j] = *(const short8*)&Bs[(wc * 32 + j * 8) * 64 + rofs];
#pragma unroll
    for (int i = 0; i < 4; ++i)
#pragma unroll
      for (int j = 0; j < 4; ++j)
        sacc[i][j] = __builtin_amdgcn_mfma_f32_16x16x32_bf16(bfv[j], af[i], sacc[i][j], 0, 0, 0);
  }

  const float scale = 0.03608439182435161f;  // 768^-0.5
  unsigned short* Wb = Wout + ((long long)b << 20);

#pragma unroll
  for (int i = 0; i < 4; ++i) {
    const int row = m0 + wr * 64 + i * 16 + l15;
    float ls = 0.0f;
#pragma unroll
    for (int j = 0; j < 4; ++j) {
      const int colb = n0 + wc * 64 + j * 16 + q * 4;
      float e0 = __expf(sacc[i][j][0] * scale);
      float e1 = __expf(sacc[i][j][1] * scale);
      float e2 = __expf(sacc[i][j][2] * scale);
      float e3 = __expf(sacc[i][j][3] * scale);
      ls += (e0 + e1) + (e2 + e3);
      *(short4v*)&Wb[(long long)row * 1024 + colb] =
        pack4(e0 * (float)gfp[i][j][0][0], e1 * (float)gfp[i][j][0][1],
              e2 * (float)gfp[i][j][1][0], e3 * (float)gfp[i][j][1][1]);
    }
    ls += __shfl_xor(ls, 16, 64);
    ls += __shfl_xor(ls, 32, 64);
    if (lane < 16) atomicAdd(&L[b * 1024 + row], ls);
  }
}

// gw[row][0..63] = softmax(q_row @ W_gp) padded with zeros (cols 49..63).
__global__ __launch_bounds__(256) void gw_kernel(
    const unsigned short* __restrict__ qkv, const unsigned short* __restrict__ WgpT,
    unsigned short* __restrict__ gw)
{
  const int wave = threadIdx.x >> 6;
  const int lane = threadIdx.x & 63;
  const long long row = (long long)blockIdx.x * 4 + wave;
  const unsigned short* q = qkv + row * 2304;
  float qv[12];
#pragma unroll
  for (int j = 0; j < 12; ++j) qv[j] = b2f(q[lane + 64 * j]);

  float logit = -1e30f;
  for (int g = 0; g < 49; ++g) {
    const unsigned short* wg = WgpT + g * 768;
    float acc = 0.0f;
#pragma unroll
    for (int j = 0; j < 12; ++j) acc += qv[j] * b2f(wg[lane + 64 * j]);
#pragma unroll
    for (int m = 1; m < 64; m <<= 1) acc += __shfl_xor(acc, m, 64);
    if (lane == g) logit = acc;
  }
  float mx = logit;
#pragma unroll
  for (int m = 1; m < 64; m <<= 1) mx = fmaxf(mx, __shfl_xor(mx, m, 64));
  const float e = (lane < 49) ? __expf(logit - mx) : 0.0f;
  float s = e;
#pragma unroll
  for (int m = 1; m < 64; m <<= 1) s += __shfl_xor(s, m, 64);
  gw[row * 64 + lane] = f2b(e / s);
}

__global__ void convert_f2b(const float* __restrict__ in, unsigned short* __restrict__ out, long long n)
{
  long long i = ((long long)blockIdx.x * 256 + threadIdx.x) * 4;
  if (i + 3 >= n) {
    for (long long k = i; k < n; ++k) out[k] = f2b(in[k]);
    return;
  }
  float4 v = *(const float4*)(in + i);
  out[i + 0] = f2b(v.x);
  out[i + 1] = f2b(v.y);
  out[i + 2] = f2b(v.z);
  out[i + 3] = f2b(v.w);
}

__global__ void transpose_f2b(const float* __restrict__ in, unsigned short* __restrict__ out,
                              int R, int C, int ldin, int ldout)
{
  __shared__ unsigned short t[32][33];
  const int c0 = blockIdx.x * 32, r0 = blockIdx.y * 32;
  for (int i = threadIdx.y; i < 32; i += 8) {
    const int r = r0 + i, c = c0 + threadIdx.x;
    if (r < R && c < C) t[i][threadIdx.x] = f2b(in[(long long)r * ldin + c]);
  }
  __syncthreads();
  for (int i = threadIdx.y; i < 32; i += 8) {
    const int r = c0 + i, c = r0 + threadIdx.x;
    if (r < C && c < R) out[(long long)r * ldout + c] = t[threadIdx.x][i];
  }
}

extern "C" void kernel_launch(void* const* d_in, const int* in_sizes, int n_in,
                              void* d_out, int out_size, void* d_ws, size_t ws_size,
                              hipStream_t stream)
{
  const float* x      = (const float*)d_in[0];
  const float* W_qkv  = (const float*)d_in[1];
  const float* b_qkv  = (const float*)d_in[2];
  const float* W_proj = (const float*)d_in[3];
  const float* b_proj = (const float*)d_in[4];
  const float* W_gp   = (const float*)d_in[5];
  const float* alpha  = (const float*)d_in[6];

  char* p = (char*)d_ws;
  auto alloc = [&](size_t bytes) { char* r = p; p += (bytes + 255) & ~255ULL; return r; };
  unsigned short* qkv    = (unsigned short*)alloc(16384ULL * 2304 * 2);   // q|k|v interleaved rows
  unsigned short* xb     = (unsigned short*)alloc(16384ULL * 768 * 2);
  unsigned short* WqkvT  = (unsigned short*)alloc(2304ULL * 768 * 2);
  unsigned short* WprojT = (unsigned short*)alloc(768ULL * 768 * 2);
  unsigned short* WgpT   = (unsigned short*)alloc(49ULL * 768 * 2);
  unsigned short* gwbuf  = (unsigned short*)alloc(16384ULL * 64 * 2);
  float*          Lbuf   = (float*)alloc(16384ULL * 4);
  unsigned short* wmat   = (unsigned short*)alloc(16ULL * 1024 * 1024 * 2);
  unsigned short* vpT    = (unsigned short*)alloc(16ULL * 768 * 1024 * 2); // (v @ W_proj)^T per batch

  const dim3 blk256(256);
  const dim3 tb(32, 8);

  // input conversions / transposes (fp32 -> bf16)
  convert_f2b<<<dim3(12288), blk256, 0, stream>>>(x, xb, 16384LL * 768);
  transpose_f2b<<<dim3(72, 24), tb, 0, stream>>>(W_qkv, WqkvT, 768, 2304, 2304, 768);
  transpose_f2b<<<dim3(24, 24), tb, 0, stream>>>(W_proj, WprojT, 768, 768, 768, 768);
  transpose_f2b<<<dim3(2, 24), tb, 0, stream>>>(W_gp, WgpT, 768, 49, 49, 768);

  // qkv = x @ W_qkv + b_qkv  (XCD-swizzled 1-D grid: 8 xcd * 16 ytiles * 18 xtiles)
  gemm_bt<1><<<dim3(2304, 1, 1), blk256, 0, stream>>>(xb, WqkvT, qkv, (float*)0,
                                                      (const float*)0, b_qkv,
                                                      768, 768, 768, 2304, 0, 0, 0, 0);

  // gw = softmax(q @ W_gp), padded to 64
  gw_kernel<<<dim3(4096), blk256, 0, stream>>>(qkv, WgpT, gwbuf);

  hipMemsetAsync(Lbuf, 0, 16384 * 4, stream);

  // weights (unnormalized) + L
  score_weights<<<dim3(8, 8, 16), blk256, 0, stream>>>(qkv, gwbuf, wmat, Lbuf, alpha);

  // vpT[b][768][1024] = (v @ W_proj)^T = W_proj^T . v^T
  //   gemm_bt: C[n][m] = sum_k WprojT[n][k] * v[m][k]; A=WprojT (shared), B=v rows of qkv
  gemm_bt<0><<<dim3(8, 6, 16), blk256, 0, stream>>>(WprojT, qkv + 1536, vpT, (float*)0,
                                                    (const float*)0, (const float*)0,
                                                    768, 768, 2304, 1024,
                                                    0, 1024LL * 2304, 768LL * 1024, 0);

  // out[m][n] = (1/L[m]) * sum_k wmat[m][k] * vpT[n][k] + b_proj[n]   (fp32 out)
  gemm_bt<0><<<dim3(6, 8, 16), blk256, 0, stream>>>(wmat, vpT, (unsigned short*)0, (float*)d_out,
                                                    Lbuf, b_proj,
                                                    1024, 1024, 1024, 768,
                                                    1024LL * 1024, 768LL * 1024, 1024LL * 768, 1024);
}